// Round 10
// baseline (2846.741 us; speedup 1.0000x reference)
//
#include <hip/hip_runtime.h>
#include <cstdint>
#include <cstddef>

typedef unsigned short u16;
typedef __bf16 bf16x8 __attribute__((ext_vector_type(8)));
typedef float  f32x4  __attribute__((ext_vector_type(4)));

#define NN 100000
#define EE 200000
#define BG 4096
#define DV 300
#define DP 320
#define D2 600
#define D2P 640
#define FEAT 512
#define FH 256
#define NL 5
#define CHUNK 50048   // 391 * 128; 2 chunks cover 100000 rows
#define QN (NN/4)     // 25000 aggr blocks, 4 nodes each

__device__ __forceinline__ float b2f(u16 u) {
    union { float f; unsigned int i; } x; x.i = ((unsigned int)u) << 16; return x.f;
}
__device__ __forceinline__ u16 f2b(float f) {
    union { float f; unsigned int i; } x; x.f = f;
    unsigned int r = (x.i + 0x7FFFu + ((x.i >> 16) & 1u)) >> 16;
    return (u16)r;
}
// mode-aware parameter load: m==1 -> fp32 data, m==0 -> bf16 data
__device__ __forceinline__ float ldp(const void* p, size_t i, int m) {
    return m ? ((const float*)p)[i] : b2f(((const u16*)p)[i]);
}

// ---------------------------------------------------------------- dtype detection
__global__ void detect_kernel(const void* w1raw, int* mode) {
    if (threadIdx.x != 0 || blockIdx.x != 0) return;
    const u16* p = (const u16*)w1raw;
    int cnt = 0;
    for (int i = 0; i < 128; ++i) {
        u16 v = p[2 * i];
        int e = (v >> 7) & 0xFF;
        if (e >= 100 && e <= 135) ++cnt;
    }
    *mode = (cnt >= 100) ? 0 : 1;   // 0 = bf16, 1 = fp32
}

// ---------------------------------------------------------------- utility
__global__ void zero_int_kernel(int* __restrict__ p, long n) {
    long i = (long)blockIdx.x * blockDim.x + threadIdx.x;
    long stride = (long)gridDim.x * blockDim.x;
    for (; i < n; i += stride) p[i] = 0;
}

__global__ void zero_stats_kernel(float* __restrict__ a, float* __restrict__ b) {
    int t = threadIdx.x; a[t] = 0.f; b[t] = 0.f;
}

// ---------------------------------------------------------------- weight packing
// W1pT rows k=0..299 from W1; k=300..307 are owned by fold_kernel (EMB@W1);
// k>=308 zero. Biases to fp32.
__global__ void pack_kernel(const void* __restrict__ W1, const void* __restrict__ W2,
                            const void* __restrict__ Wf, const void* __restrict__ Wp1,
                            const void* __restrict__ Wp2,
                            const void* __restrict__ b1, const void* __restrict__ b2,
                            const void* __restrict__ bfe, const void* __restrict__ bp1,
                            const void* __restrict__ bp2,
                            u16* __restrict__ W1pT, u16* __restrict__ W2pT,
                            u16* __restrict__ WfT, u16* __restrict__ Wp1T, u16* __restrict__ Wp2T,
                            float* __restrict__ b1p, float* __restrict__ b2p,
                            float* __restrict__ bfp, float* __restrict__ bp1p, float* __restrict__ bp2p,
                            const int* __restrict__ modep)
{
    const int m = *modep;
    const int s1 = NL*D2P*DP, s2 = NL*DP*D2P, s3 = FEAT*DP, s4 = FH*FEAT, s5 = FH*FH;
    const int s6 = NL*D2P, s7 = NL*DP, s8 = FEAT, s9 = FH, s10 = FH;
    int idx = blockIdx.x * 256 + threadIdx.x;
    if (idx < s1) { // W1pT[l][n][k]
        int l = idx / (D2P*DP), r = idx % (D2P*DP), n = r / DP, k = r % DP;
        u16 v = 0;
        if (n < D2) {
            if (k < DV) v = f2b(ldp(W1, ((size_t)l*DV + k)*D2 + n, m));
            else if (k < DV + 8) return;   // fold_kernel owns these
        }
        W1pT[idx] = v; return;
    } idx -= s1;
    if (idx < s2) { // W2pT[l][n<320][k<640] = W2[l][k][n]
        int l = idx / (DP*D2P), r = idx % (DP*D2P), n = r / D2P, k = r % D2P;
        W2pT[idx] = (n < DV && k < D2) ? f2b(ldp(W2, ((size_t)l*D2 + k)*DV + n, m)) : (u16)0; return;
    } idx -= s2;
    if (idx < s3) { int n = idx / DP, k = idx % DP;
        WfT[idx] = (k < DV) ? f2b(ldp(Wf, (size_t)k*FEAT + n, m)) : (u16)0; return; } idx -= s3;
    if (idx < s4) { int n = idx / FEAT, k = idx % FEAT;
        Wp1T[idx] = f2b(ldp(Wp1, (size_t)k*FH + n, m)); return; } idx -= s4;
    if (idx < s5) { int n = idx / FH, k = idx % FH;
        Wp2T[idx] = f2b(ldp(Wp2, (size_t)k*FH + n, m)); return; } idx -= s5;
    if (idx < s6) { int l = idx / D2P, n = idx % D2P;
        b1p[idx] = (n < D2) ? ldp(b1, l*D2 + n, m) : 0.f; return; } idx -= s6;
    if (idx < s7) { int l = idx / DP, n = idx % DP;
        b2p[idx] = (n < DV) ? ldp(b2, l*DV + n, m) : 0.f; return; } idx -= s7;
    if (idx < s8) { bfp[idx] = ldp(bfe, idx, m); return; } idx -= s8;
    if (idx < s9) { bp1p[idx] = ldp(bp1, idx, m); return; } idx -= s9;
    if (idx < s10) { bp2p[idx] = ldp(bp2, idx, m); return; }
}

// EMB @ W1 fold: W1pT[l][n][300+bin] = sum_d emb[l][bin][d] * W1[l][d][n].
// One block per (l,bin); 640 threads, n<600 active; W1 reads coalesced over n.
__global__ void fold_kernel(const void* __restrict__ W1,
                            const void* __restrict__ eemb1, const void* __restrict__ eemb2,
                            u16* __restrict__ W1pT, const int* __restrict__ modep)
{
    const int m = *modep;
    __shared__ float e[DV];
    int b = blockIdx.x;            // 0..NL*8-1
    int l = b >> 3, bin = b & 7;
    int n = threadIdx.x;
    for (int d = n; d < DV; d += 640)
        e[d] = (bin < 5) ? ldp(eemb1, ((size_t)l*5 + bin)*DV + d, m)
                         : ldp(eemb2, ((size_t)l*3 + (bin-5))*DV + d, m);
    __syncthreads();
    if (n >= D2) return;
    float acc = 0.f;
    for (int d = 0; d < DV; ++d)
        acc += e[d] * ldp(W1, ((size_t)l*DV + d)*D2 + n, m);
    W1pT[((size_t)l*D2P + n)*DP + DV + bin] = f2b(acc);
}

// ---------------------------------------------------------------- CSR build
__global__ void count_kernel(const int* __restrict__ ei, const int* __restrict__ ea,
                             int* __restrict__ indeg, int* __restrict__ cnt)
{
    int e = blockIdx.x * 256 + threadIdx.x;
    if (e >= EE) return;
    int dst = ei[EE + e];
    atomicAdd(&indeg[dst], 1);
    atomicAdd(&cnt[dst*8 + ea[e*2]], 1);
    atomicAdd(&cnt[dst*8 + 5 + ea[e*2+1]], 1);
}

__global__ void scan1_kernel(const int* __restrict__ in, int* __restrict__ out,
                             int* __restrict__ partials, int n)
{
    __shared__ int sm[256];
    int t = threadIdx.x, gi = blockIdx.x * 256 + t;
    int v = (gi < n) ? in[gi] : 0;
    sm[t] = v; __syncthreads();
    int acc = v;
    for (int off = 1; off < 256; off <<= 1) {
        int other = (t >= off) ? sm[t - off] : 0;
        __syncthreads();
        acc += other; sm[t] = acc;
        __syncthreads();
    }
    if (gi < n) out[gi] = acc - v;
    if (t == 255) partials[blockIdx.x] = acc;
}

__global__ void scan2_kernel(int* __restrict__ partials, int nb)
{
    __shared__ int sm[512];
    int t = threadIdx.x;
    int v = (t < nb) ? partials[t] : 0;
    sm[t] = v; __syncthreads();
    int acc = v;
    for (int off = 1; off < 512; off <<= 1) {
        int other = (t >= off) ? sm[t - off] : 0;
        __syncthreads();
        acc += other; sm[t] = acc;
        __syncthreads();
    }
    if (t < nb) partials[t] = acc - v;
}

__global__ void scan3_kernel(int* __restrict__ rowptr, const int* __restrict__ partials,
                             int* __restrict__ cursor, int n)
{
    int i = blockIdx.x * 256 + threadIdx.x;
    if (i < n) {
        int v = rowptr[i] + partials[i >> 8];
        rowptr[i] = v; cursor[i] = v;
    }
    if (i == n) rowptr[n] = EE;
}

__global__ void fill_kernel(const int* __restrict__ ei, int* __restrict__ cursor,
                            int* __restrict__ colidx)
{
    int e = blockIdx.x * 256 + threadIdx.x;
    if (e >= EE) return;
    int src = ei[e], dst = ei[EE + e];
    int pos = atomicAdd(&cursor[dst], 1);
    colidx[pos] = src;
}

// ---------------------------------------------------------------- node init
__global__ void h0_kernel(const int* __restrict__ x, const void* __restrict__ e1,
                          const void* __restrict__ e2, u16* __restrict__ H,
                          const int* __restrict__ modep)
{
    const int m = *modep;
    int i = blockIdx.x, d = threadIdx.x;
    u16 r = 0;
    if (d < DV) {
        int a = x[i*2], b = x[i*2+1];
        r = f2b(ldp(e1, (size_t)a*DV + d, m) + ldp(e2, (size_t)b*DV + d, m));
    }
    H[(size_t)i*DP + d] = r;
}

// ---------------------------------------------------------------- aggregation (4 nodes/block for 4x memory-level parallelism)
template<bool BN>
__global__ __launch_bounds__(320)
void aggr_kernel(const u16* __restrict__ H, const int* __restrict__ rowptr,
                 const int* __restrict__ colidx, const int* __restrict__ cnt,
                 const float* __restrict__ sc, const float* __restrict__ sh,
                 u16* __restrict__ out)
{
    const int b = blockIdx.x, d = threadIdx.x;
    int node[4];
    #pragma unroll
    for (int k = 0; k < 4; ++k) node[k] = b + k * QN;

    if (d < DV) {
        float scv = BN ? sc[d] : 1.f, shv = BN ? sh[d] : 0.f;
        float acc[4];
        int e0[4], deg[4]; int maxdeg = 0;
        #pragma unroll
        for (int k = 0; k < 4; ++k) {
            e0[k] = rowptr[node[k]];
            deg[k] = rowptr[node[k] + 1] - e0[k];
            maxdeg = max(maxdeg, deg[k]);
            float h = b2f(H[(size_t)node[k]*DP + d]);
            if (BN) h = fmaxf(h * scv + shv, 0.f);
            acc[k] = h;
        }
        for (int j = 0; j < maxdeg; ++j) {
            int idx[4];
            #pragma unroll
            for (int k = 0; k < 4; ++k) {
                int jj = e0[k] + j; if (jj > EE - 1) jj = EE - 1;
                idx[k] = (j < deg[k]) ? colidx[jj] : node[k];
            }
            float hv[4];
            #pragma unroll
            for (int k = 0; k < 4; ++k) hv[k] = b2f(H[(size_t)idx[k]*DP + d]);
            #pragma unroll
            for (int k = 0; k < 4; ++k) {
                float h = hv[k];
                if (BN) h = fmaxf(h * scv + shv, 0.f);
                if (j < deg[k]) acc[k] += h;
            }
        }
        #pragma unroll
        for (int k = 0; k < 4; ++k) out[(size_t)node[k]*DP + d] = f2b(acc[k]);
    } else {
        #pragma unroll
        for (int k = 0; k < 4; ++k) {
            float v = 0.f;
            if (d < DV + 8) {
                int c = cnt[node[k]*8 + (d - DV)];
                if (d == DV + 4 || d == DV + 5) c += 1;   // self-loop attr (4,0)
                v = (float)c;
            }
            out[(size_t)node[k]*DP + d] = f2b(v);
        }
    }
}

// ---------------------------------------------------------------- bf16 MFMA GEMM
// 128x128 tile, 2 waves/block (each wave: 64 rows x 128 cols = 4x8 MFMA tiles,
// 64 MFMA per BK=64 step -> 4x the MFMA:barrier ratio of the 4-wave version).
// BK=64, XOR-swizzled LDS, XCD-aware tile swizzle (1D grid padded to x8).
// EPI: 0 none, 1 relu, 2 softplus. STATS: fused per-column BN sums.
template<int EPI, bool F32OUT, bool STATS>
__global__ __launch_bounds__(128)
void gemm_bt(const u16* __restrict__ A, int lda,
             const u16* __restrict__ Bt,
             const float* __restrict__ bias,
             u16* __restrict__ C, float* __restrict__ Cf, int ldc,
             int M, int Ncols, int K,
             float* __restrict__ cs, float* __restrict__ cs2)
{
    const int MT = (M + 127) >> 7, NT = (Ncols + 127) >> 7;
    const int total = MT * NT;
    int id = blockIdx.x;
    int nper = (total + 7) >> 3;
    int slot = (id & 7) * nper + (id >> 3);   // transpose over XCDs: n-tiles run on one XCD
    if (slot >= total) return;
    const int m0 = (slot / NT) * 128;
    const int n0 = (slot % NT) * 128;

    __shared__ __align__(16) u16 As[128*64];
    __shared__ __align__(16) u16 Bs[128*64];
    const int t = threadIdx.x;
    const int w = t >> 6, l = t & 63;
    const int wm = w * 64;                    // wave's row strip
    const int srow = l >> 3;                  // row within 8-row staging chunk
    const int sg   = ((l & 7) ^ srow) * 8;    // swizzled k-granule offset (elems)
    const int fr = l & 15, q = l >> 4;

    f32x4 acc[4][8] = {};

    for (int k0 = 0; k0 < K; k0 += 64) {
        #pragma unroll
        for (int i = 0; i < 8; ++i) {
            int cc = w * 8 + i;               // 0..15, wave-uniform
            int rl = cc * 8 + srow;           // local row 0..127
            {   // A tile
                int row = m0 + rl; if (row >= M) row = M - 1;
                const u16* gp = A + (size_t)row * lda + (k0 + sg);
                __builtin_amdgcn_global_load_lds((__attribute__((address_space(1))) void*)gp,
                                                 (__attribute__((address_space(3))) void*)(As + cc*512), 16, 0, 0);
            }
            {   // B tile
                int row = n0 + rl; if (row >= Ncols) row = Ncols - 1;
                const u16* gp = Bt + (size_t)row * K + (k0 + sg);
                __builtin_amdgcn_global_load_lds((__attribute__((address_space(1))) void*)gp,
                                                 (__attribute__((address_space(3))) void*)(Bs + cc*512), 16, 0, 0);
            }
        }
        asm volatile("s_waitcnt vmcnt(0)" ::: "memory");
        __syncthreads();

        #pragma unroll
        for (int s = 0; s < 2; ++s) {
            bf16x8 af[4], bv[8];
            #pragma unroll
            for (int mi = 0; mi < 4; ++mi) {
                int R = wm + mi*16 + fr;
                int g = (s*4 + q) ^ (R & 7);
                af[mi] = *reinterpret_cast<const bf16x8*>(As + R*64 + g*8);
            }
            #pragma unroll
            for (int ni = 0; ni < 8; ++ni) {
                int R = ni*16 + fr;
                int g = (s*4 + q) ^ (R & 7);
                bv[ni] = *reinterpret_cast<const bf16x8*>(Bs + R*64 + g*8);
            }
            #pragma unroll
            for (int mi = 0; mi < 4; ++mi)
                #pragma unroll
                for (int ni = 0; ni < 8; ++ni)
                    acc[mi][ni] = __builtin_amdgcn_mfma_f32_16x16x32_bf16(af[mi], bv[ni], acc[mi][ni], 0, 0, 0);
        }
        __syncthreads();
    }

    const int orow = q * 4, ocol = l & 15;
    #pragma unroll
    for (int ni = 0; ni < 8; ++ni) {
        int col = n0 + ni*16 + ocol;
        if (col >= Ncols) continue;           // uniform across the 16-lane ocol group
        float bvv = bias[col];
        float s = 0.f, s2 = 0.f;
        #pragma unroll
        for (int mi = 0; mi < 4; ++mi) {
            #pragma unroll
            for (int r = 0; r < 4; ++r) {
                int row = m0 + wm + mi*16 + orow + r;
                if (row < M) {
                    float v = acc[mi][ni][r] + bvv;
                    if (EPI == 1) v = fmaxf(v, 0.f);
                    else if (EPI == 2) v = fmaxf(v, 0.f) + log1pf(expf(-fabsf(v)));
                    C[(size_t)row * ldc + col] = f2b(v);
                    if (F32OUT) Cf[(size_t)row * ldc + col] = v;
                    if (STATS) { s += v; s2 += v * v; }
                }
            }
        }
        if (STATS) {
            s  += __shfl_xor(s, 16);  s  += __shfl_xor(s, 32);
            s2 += __shfl_xor(s2, 16); s2 += __shfl_xor(s2, 32);
            if (q == 0) {
                atomicAdd(&cs[col], s);
                atomicAdd(&cs2[col], s2);
            }
        }
    }
}

// ---------------------------------------------------------------- BN finalize (stats accumulated by GEMM2 epilogue)
__global__ void bn_finalize(const float* __restrict__ cs, const float* __restrict__ cs2,
                            const void* __restrict__ gamma, const void* __restrict__ beta,
                            int goff, float* __restrict__ sc, float* __restrict__ sh,
                            const int* __restrict__ modep)
{
    const int m = *modep;
    int d = threadIdx.x;
    float a = 0.f, bb = 0.f;
    if (d < DV) {
        float mu = cs[d] / (float)NN;
        float var = cs2[d] / (float)NN - mu * mu;
        var = fmaxf(var, 0.f);
        a = ldp(gamma, goff + d, m) * rsqrtf(var + 1e-5f);
        bb = ldp(beta, goff + d, m) - mu * a;
    }
    sc[d] = a; sh[d] = bb;
}

// ---------------------------------------------------------------- pooling (block/graph, 4 waves, LDS reduce; applies last BN affine)
__global__ void gstart_kernel(const int* __restrict__ batch, int* __restrict__ gs)
{
    int i = blockIdx.x * 256 + threadIdx.x;
    if (i >= NN) return;
    int b = batch[i];
    int pb = (i == 0) ? -1 : batch[i-1];
    for (int g = pb + 1; g <= b; ++g) gs[g] = i;
    if (i == NN - 1) for (int g = b + 1; g <= BG; ++g) gs[g] = NN;
}

__global__ __launch_bounds__(256)
void pool_kernel(const u16* __restrict__ H, const int* __restrict__ gs,
                 const float* __restrict__ sc, const float* __restrict__ sh,
                 u16* __restrict__ pooled)
{
    __shared__ float red[4][320];
    int b = blockIdx.x;
    int wv = threadIdx.x >> 6, lane = threadIdx.x & 63;
    int s = gs[b], e = gs[b+1];
    if (lane < 40) {
        int d0 = lane * 8;
        float a[8] = {0.f,0.f,0.f,0.f,0.f,0.f,0.f,0.f};
        for (int r = s + wv; r < e; r += 4) {
            uint4 row = *(const uint4*)(H + (size_t)r * DP + d0);
            const u16* p = (const u16*)&row;
            #pragma unroll
            for (int j = 0; j < 8; ++j) a[j] += b2f(p[j]);
        }
        #pragma unroll
        for (int j = 0; j < 8; ++j) red[wv][d0 + j] = a[j];
    }
    __syncthreads();
    if (wv == 0 && lane < 40) {
        int d0 = lane * 8;
        int c = e - s; if (c < 1) c = 1;
        float inv = 1.f / (float)c;
        union { uint4 v; u16 o[8]; } pk;
        #pragma unroll
        for (int j = 0; j < 8; ++j) {
            int d = d0 + j;
            float m = (red[0][d] + red[1][d] + red[2][d] + red[3][d]) * inv;
            pk.o[j] = f2b(m * sc[d] + sh[d]);
        }
        *(uint4*)(pooled + (size_t)b * DP + d0) = pk.v;
    }
}

// ---------------------------------------------------------------- final tiny GEMV (K=256 -> 2 fp32 outputs)
__global__ void pred_kernel(const u16* __restrict__ P2, const void* __restrict__ W3,
                            const void* __restrict__ b3, float* __restrict__ out,
                            const int* __restrict__ modep)
{
    const int m = *modep;
    int r = blockIdx.x, l = threadIdx.x;
    float a0 = 0.f, a1 = 0.f;
    for (int k = l; k < FH; k += 64) {
        float p = b2f(P2[(size_t)r*FH + k]);
        a0 += p * ldp(W3, k*2, m);
        a1 += p * ldp(W3, k*2 + 1, m);
    }
    for (int o = 32; o > 0; o >>= 1) {
        a0 += __shfl_down(a0, o);
        a1 += __shfl_down(a1, o);
    }
    if (l == 0) {
        out[(size_t)r*2]     = a0 + ldp(b3, 0, m);
        out[(size_t)r*2 + 1] = a1 + ldp(b3, 1, m);
    }
}

static inline int gemm_grid(int M, int Ncols) {
    int total = ((M + 127) / 128) * ((Ncols + 127) / 128);
    return ((total + 7) / 8) * 8;
}

// ---------------------------------------------------------------- launch
extern "C" void kernel_launch(void* const* d_in, const int* in_sizes, int n_in,
                              void* d_out, int out_size, void* d_ws, size_t ws_size,
                              hipStream_t stream)
{
    const int* x      = (const int*)d_in[0];
    const int* ei     = (const int*)d_in[1];
    const int* ea     = (const int*)d_in[2];
    const int* batch  = (const int*)d_in[3];
    const void* x_emb1 = d_in[4];
    const void* x_emb2 = d_in[5];
    const void* eemb1  = d_in[6];
    const void* eemb2  = d_in[7];
    const void* W1     = d_in[8];
    const void* b1     = d_in[9];
    const void* W2     = d_in[10];
    const void* b2     = d_in[11];
    const void* gamma  = d_in[12];
    const void* beta   = d_in[13];
    const void* Wf     = d_in[14];
    const void* bfe    = d_in[15];
    const void* Wp1    = d_in[16];
    const void* bp1    = d_in[17];
    const void* Wp2    = d_in[18];
    const void* bp2    = d_in[19];
    const void* Wp3    = d_in[20];
    const void* bp3    = d_in[21];
    float* outf = (float*)d_out;   // fp32 output: hf [4096*512] then pred [4096*2]

    char* ws = (char*)d_ws;
    size_t off = 0;
    auto carve = [&](size_t bytes) -> char* {
        size_t a = (off + 255) & ~(size_t)255; off = a + bytes; return ws + a;
    };

    u16* H      = (u16*)carve((size_t)NN * DP * 2);      // 64.0 MB (pre-BN after each layer)
    u16* AGGR   = (u16*)carve((size_t)NN * DP * 2);      // 64.0 MB
    u16* T      = (u16*)carve((size_t)CHUNK * D2P * 2);  // 64.1 MB (2 chunks)
    u16* POOLED = (u16*)carve((size_t)BG * DP * 2);
    u16* HFB    = (u16*)carve((size_t)BG * FEAT * 2);    // bf16 copy of hf for the MLP head
    u16* P1     = (u16*)carve((size_t)BG * FH * 2);
    u16* P2     = (u16*)carve((size_t)BG * FH * 2);
    u16* W1pT   = (u16*)carve((size_t)NL * D2P * DP * 2);
    u16* W2pT   = (u16*)carve((size_t)NL * DP * D2P * 2);
    u16* WfT    = (u16*)carve((size_t)FEAT * DP * 2);
    u16* Wp1T   = (u16*)carve((size_t)FH * FEAT * 2);
    u16* Wp2T   = (u16*)carve((size_t)FH * FH * 2);
    float* B1P  = (float*)carve((size_t)NL * D2P * 4);
    float* B2P  = (float*)carve((size_t)NL * DP * 4);
    float* BFP  = (float*)carve((size_t)FEAT * 4);
    float* BP1P = (float*)carve((size_t)FH * 4);
    float* BP2P = (float*)carve((size_t)FH * 4);
    int* INDEG  = (int*)carve((size_t)9 * NN * 4);   // indeg [N] then cnt [N*8]
    int* CNT    = INDEG + NN;
    int* ROWPTR = (int*)carve((size_t)(NN + 1) * 4);
    int* CURSOR = (int*)carve((size_t)NN * 4);
    int* COLIDX = (int*)carve((size_t)EE * 4);
    int* PART   = (int*)carve(512 * 4);
    float* CS   = (float*)carve(DP * 4);                 // fused BN stats (col sums)
    float* CS2  = (float*)carve(DP * 4);
    float* BNSC = (float*)carve((size_t)NL * DP * 4);    // per-layer BN scale
    float* BNSH = (float*)carve((size_t)NL * DP * 4);    // per-layer BN shift
    int* GS     = (int*)carve((size_t)(BG + 1) * 4);
    int* MODEP  = (int*)carve(4);
    (void)ws_size; (void)in_sizes; (void)n_in; (void)out_size;

    detect_kernel<<<1, 64, 0, stream>>>(W1, MODEP);

    const int PACK_TOTAL = NL*D2P*DP + NL*DP*D2P + FEAT*DP + FH*FEAT + FH*FH
                         + NL*D2P + NL*DP + FEAT + FH + FH;
    pack_kernel<<<(PACK_TOTAL + 255)/256, 256, 0, stream>>>(
        W1, W2, Wf, Wp1, Wp2, b1, b2, bfe, bp1, bp2,
        W1pT, W2pT, WfT, Wp1T, Wp2T, B1P, B2P, BFP, BP1P, BP2P, MODEP);
    fold_kernel<<<NL*8, 640, 0, stream>>>(W1, eemb1, eemb2, W1pT, MODEP);

    zero_int_kernel<<<2048, 256, 0, stream>>>(INDEG, (long)9 * NN);
    count_kernel<<<(EE + 255)/256, 256, 0, stream>>>(ei, ea, INDEG, CNT);

    const int NB = (NN + 255) / 256; // 391
    scan1_kernel<<<NB, 256, 0, stream>>>(INDEG, ROWPTR, PART, NN);
    scan2_kernel<<<1, 512, 0, stream>>>(PART, NB);
    scan3_kernel<<<(NN + 256)/256, 256, 0, stream>>>(ROWPTR, PART, CURSOR, NN);
    fill_kernel<<<(EE + 255)/256, 256, 0, stream>>>(ei, CURSOR, COLIDX);

    h0_kernel<<<NN, DP, 0, stream>>>(x, x_emb1, x_emb2, H, MODEP);
    gstart_kernel<<<(NN + 255)/256, 256, 0, stream>>>(batch, GS);

    for (int l = 0; l < NL; ++l) {
        if (l == 0)
            aggr_kernel<false><<<QN, DP, 0, stream>>>(H, ROWPTR, COLIDX, CNT,
                                                      nullptr, nullptr, AGGR);
        else
            aggr_kernel<true><<<QN, DP, 0, stream>>>(H, ROWPTR, COLIDX, CNT,
                                                     BNSC + (l-1)*DP, BNSH + (l-1)*DP, AGGR);
        zero_stats_kernel<<<1, DP, 0, stream>>>(CS, CS2);
        // GEMM1 -> relu -> T, GEMM2 -> H (pre-BN) + fused BN stats, chunked
        for (int r0 = 0; r0 < NN; r0 += CHUNK) {
            int mc = NN - r0; if (mc > CHUNK) mc = CHUNK;
            gemm_bt<1,false,false><<<gemm_grid(mc, D2P), 128, 0, stream>>>(
                AGGR + (size_t)r0*DP, DP, W1pT + (size_t)l*D2P*DP,
                B1P + l*D2P, T, nullptr, D2P, mc, D2P, DP, nullptr, nullptr);
            gemm_bt<0,false,true><<<gemm_grid(mc, DP), 128, 0, stream>>>(
                T, D2P, W2pT + (size_t)l*DP*D2P,
                B2P + l*DP, H + (size_t)r0*DP, nullptr, DP, mc, DP, D2P, CS, CS2);
        }
        bn_finalize<<<1, DP, 0, stream>>>(CS, CS2, gamma, beta, l*DV,
                                          BNSC + l*DP, BNSH + l*DP, MODEP);
    }

    pool_kernel<<<BG, 256, 0, stream>>>(H, GS, BNSC + 4*DP, BNSH + 4*DP, POOLED);
    // hf: fp32 -> d_out[0 : 4096*512], bf16 copy -> HFB for the MLP head
    gemm_bt<0,true,false><<<gemm_grid(BG, FEAT), 128, 0, stream>>>(
        POOLED, DP, WfT, BFP, HFB, outf, FEAT, BG, FEAT, DP, nullptr, nullptr);
    gemm_bt<2,false,false><<<gemm_grid(BG, FH), 128, 0, stream>>>(
        HFB, FEAT, Wp1T, BP1P, P1, nullptr, FH, BG, FH, FEAT, nullptr, nullptr);
    gemm_bt<2,false,false><<<gemm_grid(BG, FH), 128, 0, stream>>>(
        P1, FH, Wp2T, BP2P, P2, nullptr, FH, BG, FH, FH, nullptr, nullptr);
    pred_kernel<<<BG, 64, 0, stream>>>(P2, Wp3, bp3, outf + (size_t)BG*FEAT, MODEP);
}

// Round 11
// 1860.093 us; speedup vs baseline: 1.5304x; 1.5304x over previous
//
#include <hip/hip_runtime.h>
#include <cstdint>
#include <cstddef>

typedef unsigned short u16;
typedef __bf16 bf16x8 __attribute__((ext_vector_type(8)));
typedef float  f32x4  __attribute__((ext_vector_type(4)));

#define NN 100000
#define EE 200000
#define BG 4096
#define DV 300
#define DP 320
#define D2 600
#define D2P 640
#define FEAT 512
#define FH 256
#define NL 5
#define CHUNK 50048   // 391 * 128; 2 chunks cover 100000 rows
#define QN (NN/4)     // 25000 aggr blocks, 4 nodes each

__device__ __forceinline__ float b2f(u16 u) {
    union { float f; unsigned int i; } x; x.i = ((unsigned int)u) << 16; return x.f;
}
__device__ __forceinline__ u16 f2b(float f) {
    union { float f; unsigned int i; } x; x.f = f;
    unsigned int r = (x.i + 0x7FFFu + ((x.i >> 16) & 1u)) >> 16;
    return (u16)r;
}
// mode-aware parameter load: m==1 -> fp32 data, m==0 -> bf16 data
__device__ __forceinline__ float ldp(const void* p, size_t i, int m) {
    return m ? ((const float*)p)[i] : b2f(((const u16*)p)[i]);
}

// ---------------------------------------------------------------- dtype detection
__global__ void detect_kernel(const void* w1raw, int* mode) {
    if (threadIdx.x != 0 || blockIdx.x != 0) return;
    const u16* p = (const u16*)w1raw;
    int cnt = 0;
    for (int i = 0; i < 128; ++i) {
        u16 v = p[2 * i];
        int e = (v >> 7) & 0xFF;
        if (e >= 100 && e <= 135) ++cnt;
    }
    *mode = (cnt >= 100) ? 0 : 1;   // 0 = bf16, 1 = fp32
}

// ---------------------------------------------------------------- utility
__global__ void zero_int_kernel(int* __restrict__ p, long n) {
    long i = (long)blockIdx.x * blockDim.x + threadIdx.x;
    long stride = (long)gridDim.x * blockDim.x;
    for (; i < n; i += stride) p[i] = 0;
}

__global__ void zero_stats_kernel(float* __restrict__ a, float* __restrict__ b) {
    int t = threadIdx.x; a[t] = 0.f; b[t] = 0.f;
}

// ---------------------------------------------------------------- weight packing
// W1pT rows k=0..299 from W1; k=300..307 are owned by fold_kernel (EMB@W1);
// k>=308 zero. Biases to fp32.
__global__ void pack_kernel(const void* __restrict__ W1, const void* __restrict__ W2,
                            const void* __restrict__ Wf, const void* __restrict__ Wp1,
                            const void* __restrict__ Wp2,
                            const void* __restrict__ b1, const void* __restrict__ b2,
                            const void* __restrict__ bfe, const void* __restrict__ bp1,
                            const void* __restrict__ bp2,
                            u16* __restrict__ W1pT, u16* __restrict__ W2pT,
                            u16* __restrict__ WfT, u16* __restrict__ Wp1T, u16* __restrict__ Wp2T,
                            float* __restrict__ b1p, float* __restrict__ b2p,
                            float* __restrict__ bfp, float* __restrict__ bp1p, float* __restrict__ bp2p,
                            const int* __restrict__ modep)
{
    const int m = *modep;
    const int s1 = NL*D2P*DP, s2 = NL*DP*D2P, s3 = FEAT*DP, s4 = FH*FEAT, s5 = FH*FH;
    const int s6 = NL*D2P, s7 = NL*DP, s8 = FEAT, s9 = FH, s10 = FH;
    int idx = blockIdx.x * 256 + threadIdx.x;
    if (idx < s1) { // W1pT[l][n][k]
        int l = idx / (D2P*DP), r = idx % (D2P*DP), n = r / DP, k = r % DP;
        u16 v = 0;
        if (n < D2) {
            if (k < DV) v = f2b(ldp(W1, ((size_t)l*DV + k)*D2 + n, m));
            else if (k < DV + 8) return;   // fold_kernel owns these
        }
        W1pT[idx] = v; return;
    } idx -= s1;
    if (idx < s2) { // W2pT[l][n<320][k<640] = W2[l][k][n]
        int l = idx / (DP*D2P), r = idx % (DP*D2P), n = r / D2P, k = r % D2P;
        W2pT[idx] = (n < DV && k < D2) ? f2b(ldp(W2, ((size_t)l*D2 + k)*DV + n, m)) : (u16)0; return;
    } idx -= s2;
    if (idx < s3) { int n = idx / DP, k = idx % DP;
        WfT[idx] = (k < DV) ? f2b(ldp(Wf, (size_t)k*FEAT + n, m)) : (u16)0; return; } idx -= s3;
    if (idx < s4) { int n = idx / FEAT, k = idx % FEAT;
        Wp1T[idx] = f2b(ldp(Wp1, (size_t)k*FH + n, m)); return; } idx -= s4;
    if (idx < s5) { int n = idx / FH, k = idx % FH;
        Wp2T[idx] = f2b(ldp(Wp2, (size_t)k*FH + n, m)); return; } idx -= s5;
    if (idx < s6) { int l = idx / D2P, n = idx % D2P;
        b1p[idx] = (n < D2) ? ldp(b1, l*D2 + n, m) : 0.f; return; } idx -= s6;
    if (idx < s7) { int l = idx / DP, n = idx % DP;
        b2p[idx] = (n < DV) ? ldp(b2, l*DV + n, m) : 0.f; return; } idx -= s7;
    if (idx < s8) { bfp[idx] = ldp(bfe, idx, m); return; } idx -= s8;
    if (idx < s9) { bp1p[idx] = ldp(bp1, idx, m); return; } idx -= s9;
    if (idx < s10) { bp2p[idx] = ldp(bp2, idx, m); return; }
}

// EMB @ W1 fold: W1pT[l][n][300+bin] = sum_d emb[l][bin][d] * W1[l][d][n].
// One block per (l,bin); 640 threads, n<600 active; W1 reads coalesced over n.
__global__ void fold_kernel(const void* __restrict__ W1,
                            const void* __restrict__ eemb1, const void* __restrict__ eemb2,
                            u16* __restrict__ W1pT, const int* __restrict__ modep)
{
    const int m = *modep;
    __shared__ float e[DV];
    int b = blockIdx.x;            // 0..NL*8-1
    int l = b >> 3, bin = b & 7;
    int n = threadIdx.x;
    for (int d = n; d < DV; d += 640)
        e[d] = (bin < 5) ? ldp(eemb1, ((size_t)l*5 + bin)*DV + d, m)
                         : ldp(eemb2, ((size_t)l*3 + (bin-5))*DV + d, m);
    __syncthreads();
    if (n >= D2) return;
    float acc = 0.f;
    for (int d = 0; d < DV; ++d)
        acc += e[d] * ldp(W1, ((size_t)l*DV + d)*D2 + n, m);
    W1pT[((size_t)l*D2P + n)*DP + DV + bin] = f2b(acc);
}

// ---------------------------------------------------------------- CSR build
__global__ void count_kernel(const int* __restrict__ ei, const int* __restrict__ ea,
                             int* __restrict__ indeg, int* __restrict__ cnt)
{
    int e = blockIdx.x * 256 + threadIdx.x;
    if (e >= EE) return;
    int dst = ei[EE + e];
    atomicAdd(&indeg[dst], 1);
    atomicAdd(&cnt[dst*8 + ea[e*2]], 1);
    atomicAdd(&cnt[dst*8 + 5 + ea[e*2+1]], 1);
}

__global__ void scan1_kernel(const int* __restrict__ in, int* __restrict__ out,
                             int* __restrict__ partials, int n)
{
    __shared__ int sm[256];
    int t = threadIdx.x, gi = blockIdx.x * 256 + t;
    int v = (gi < n) ? in[gi] : 0;
    sm[t] = v; __syncthreads();
    int acc = v;
    for (int off = 1; off < 256; off <<= 1) {
        int other = (t >= off) ? sm[t - off] : 0;
        __syncthreads();
        acc += other; sm[t] = acc;
        __syncthreads();
    }
    if (gi < n) out[gi] = acc - v;
    if (t == 255) partials[blockIdx.x] = acc;
}

__global__ void scan2_kernel(int* __restrict__ partials, int nb)
{
    __shared__ int sm[512];
    int t = threadIdx.x;
    int v = (t < nb) ? partials[t] : 0;
    sm[t] = v; __syncthreads();
    int acc = v;
    for (int off = 1; off < 512; off <<= 1) {
        int other = (t >= off) ? sm[t - off] : 0;
        __syncthreads();
        acc += other; sm[t] = acc;
        __syncthreads();
    }
    if (t < nb) partials[t] = acc - v;
}

__global__ void scan3_kernel(int* __restrict__ rowptr, const int* __restrict__ partials,
                             int* __restrict__ cursor, int n)
{
    int i = blockIdx.x * 256 + threadIdx.x;
    if (i < n) {
        int v = rowptr[i] + partials[i >> 8];
        rowptr[i] = v; cursor[i] = v;
    }
    if (i == n) rowptr[n] = EE;
}

__global__ void fill_kernel(const int* __restrict__ ei, int* __restrict__ cursor,
                            int* __restrict__ colidx)
{
    int e = blockIdx.x * 256 + threadIdx.x;
    if (e >= EE) return;
    int src = ei[e], dst = ei[EE + e];
    int pos = atomicAdd(&cursor[dst], 1);
    colidx[pos] = src;
}

// ---------------------------------------------------------------- node init
__global__ void h0_kernel(const int* __restrict__ x, const void* __restrict__ e1,
                          const void* __restrict__ e2, u16* __restrict__ H,
                          const int* __restrict__ modep)
{
    const int m = *modep;
    int i = blockIdx.x, d = threadIdx.x;
    u16 r = 0;
    if (d < DV) {
        int a = x[i*2], b = x[i*2+1];
        r = f2b(ldp(e1, (size_t)a*DV + d, m) + ldp(e2, (size_t)b*DV + d, m));
    }
    H[(size_t)i*DP + d] = r;
}

// ---------------------------------------------------------------- aggregation (4 nodes/block for 4x memory-level parallelism)
template<bool BN>
__global__ __launch_bounds__(320)
void aggr_kernel(const u16* __restrict__ H, const int* __restrict__ rowptr,
                 const int* __restrict__ colidx, const int* __restrict__ cnt,
                 const float* __restrict__ sc, const float* __restrict__ sh,
                 u16* __restrict__ out)
{
    const int b = blockIdx.x, d = threadIdx.x;
    int node[4];
    #pragma unroll
    for (int k = 0; k < 4; ++k) node[k] = b + k * QN;

    if (d < DV) {
        float scv = BN ? sc[d] : 1.f, shv = BN ? sh[d] : 0.f;
        float acc[4];
        int e0[4], deg[4]; int maxdeg = 0;
        #pragma unroll
        for (int k = 0; k < 4; ++k) {
            e0[k] = rowptr[node[k]];
            deg[k] = rowptr[node[k] + 1] - e0[k];
            maxdeg = max(maxdeg, deg[k]);
            float h = b2f(H[(size_t)node[k]*DP + d]);
            if (BN) h = fmaxf(h * scv + shv, 0.f);
            acc[k] = h;
        }
        for (int j = 0; j < maxdeg; ++j) {
            int idx[4];
            #pragma unroll
            for (int k = 0; k < 4; ++k) {
                int jj = e0[k] + j; if (jj > EE - 1) jj = EE - 1;
                idx[k] = (j < deg[k]) ? colidx[jj] : node[k];
            }
            float hv[4];
            #pragma unroll
            for (int k = 0; k < 4; ++k) hv[k] = b2f(H[(size_t)idx[k]*DP + d]);
            #pragma unroll
            for (int k = 0; k < 4; ++k) {
                float h = hv[k];
                if (BN) h = fmaxf(h * scv + shv, 0.f);
                if (j < deg[k]) acc[k] += h;
            }
        }
        #pragma unroll
        for (int k = 0; k < 4; ++k) out[(size_t)node[k]*DP + d] = f2b(acc[k]);
    } else {
        #pragma unroll
        for (int k = 0; k < 4; ++k) {
            float v = 0.f;
            if (d < DV + 8) {
                int c = cnt[node[k]*8 + (d - DV)];
                if (d == DV + 4 || d == DV + 5) c += 1;   // self-loop attr (4,0)
                v = (float)c;
            }
            out[(size_t)node[k]*DP + d] = f2b(v);
        }
    }
}

// ---------------------------------------------------------------- bf16 MFMA GEMM (R9 config: 4 waves, 2x2 wave grid, VGPR~72,
// 5 blocks/CU — occupancy is the governing variable at short K; R10's 2-wave
// register-fat variant dropped occupancy to ~8% and regressed 1.5x)
// 128x128 tile, BK=64, XOR-swizzled LDS, XCD-aware tile swizzle (1D grid, x8 pad).
// EPI: 0 none, 1 relu, 2 softplus. STATS: fused per-column BN sums.
template<int EPI, bool F32OUT, bool STATS>
__global__ __launch_bounds__(256)
void gemm_bt(const u16* __restrict__ A, int lda,
             const u16* __restrict__ Bt,
             const float* __restrict__ bias,
             u16* __restrict__ C, float* __restrict__ Cf, int ldc,
             int M, int Ncols, int K,
             float* __restrict__ cs, float* __restrict__ cs2)
{
    const int MT = (M + 127) >> 7, NT = (Ncols + 127) >> 7;
    const int total = MT * NT;
    int id = blockIdx.x;
    int nper = (total + 7) >> 3;
    int slot = (id & 7) * nper + (id >> 3);   // transpose over XCDs: n-tiles run on one XCD
    if (slot >= total) return;
    const int m0 = (slot / NT) * 128;
    const int n0 = (slot % NT) * 128;

    __shared__ __align__(16) u16 As[128*64];
    __shared__ __align__(16) u16 Bs[128*64];
    const int t = threadIdx.x;
    const int w = t >> 6, l = t & 63;
    const int wm = (w & 1) * 64, wn = (w >> 1) * 64;
    const int srow = l >> 3;                         // row within 8-row chunk
    const int sg   = ((l & 7) ^ srow) * 8;           // swizzled k-granule offset (elems)
    const int fr = l & 15, q = l >> 4;

    f32x4 acc[4][4] = {};

    for (int k0 = 0; k0 < K; k0 += 64) {
        #pragma unroll
        for (int i = 0; i < 8; ++i) {
            int cc = w * 8 + i;                      // 0..31, wave-uniform
            int rl = (cc & 15) * 8 + srow;           // local row 0..127
            if (cc < 16) {                           // A tile
                int row = m0 + rl; if (row >= M) row = M - 1;
                const u16* gp = A + (size_t)row * lda + (k0 + sg);
                __builtin_amdgcn_global_load_lds((__attribute__((address_space(1))) void*)gp,
                                                 (__attribute__((address_space(3))) void*)(As + cc*512), 16, 0, 0);
            } else {                                 // B tile
                int row = n0 + rl; if (row >= Ncols) row = Ncols - 1;
                const u16* gp = Bt + (size_t)row * K + (k0 + sg);
                __builtin_amdgcn_global_load_lds((__attribute__((address_space(1))) void*)gp,
                                                 (__attribute__((address_space(3))) void*)(Bs + (cc-16)*512), 16, 0, 0);
            }
        }
        asm volatile("s_waitcnt vmcnt(0)" ::: "memory");
        __syncthreads();

        #pragma unroll
        for (int s = 0; s < 2; ++s) {
            bf16x8 af[4], bv[4];
            #pragma unroll
            for (int mi = 0; mi < 4; ++mi) {
                int R = wm + mi*16 + fr;
                int g = (s*4 + q) ^ (R & 7);
                af[mi] = *reinterpret_cast<const bf16x8*>(As + R*64 + g*8);
            }
            #pragma unroll
            for (int ni = 0; ni < 4; ++ni) {
                int R = wn + ni*16 + fr;
                int g = (s*4 + q) ^ (R & 7);
                bv[ni] = *reinterpret_cast<const bf16x8*>(Bs + R*64 + g*8);
            }
            #pragma unroll
            for (int mi = 0; mi < 4; ++mi)
                #pragma unroll
                for (int ni = 0; ni < 4; ++ni)
                    acc[mi][ni] = __builtin_amdgcn_mfma_f32_16x16x32_bf16(af[mi], bv[ni], acc[mi][ni], 0, 0, 0);
        }
        __syncthreads();
    }

    const int orow = q * 4, ocol = l & 15;
    #pragma unroll
    for (int ni = 0; ni < 4; ++ni) {
        int col = n0 + wn + ni*16 + ocol;
        if (col >= Ncols) continue;              // uniform across the 16-lane ocol group
        float bvv = bias[col];
        float s = 0.f, s2 = 0.f;
        #pragma unroll
        for (int mi = 0; mi < 4; ++mi) {
            #pragma unroll
            for (int r = 0; r < 4; ++r) {
                int row = m0 + wm + mi*16 + orow + r;
                if (row < M) {
                    float v = acc[mi][ni][r] + bvv;
                    if (EPI == 1) v = fmaxf(v, 0.f);
                    else if (EPI == 2) v = fmaxf(v, 0.f) + log1pf(expf(-fabsf(v)));
                    C[(size_t)row * ldc + col] = f2b(v);
                    if (F32OUT) Cf[(size_t)row * ldc + col] = v;
                    if (STATS) { s += v; s2 += v * v; }
                }
            }
        }
        if (STATS) {
            s  += __shfl_xor(s, 16);  s  += __shfl_xor(s, 32);
            s2 += __shfl_xor(s2, 16); s2 += __shfl_xor(s2, 32);
            if (q == 0) {
                atomicAdd(&cs[col], s);
                atomicAdd(&cs2[col], s2);
            }
        }
    }
}

// ---------------------------------------------------------------- BN finalize (stats accumulated by GEMM2 epilogue)
__global__ void bn_finalize(const float* __restrict__ cs, const float* __restrict__ cs2,
                            const void* __restrict__ gamma, const void* __restrict__ beta,
                            int goff, float* __restrict__ sc, float* __restrict__ sh,
                            const int* __restrict__ modep)
{
    const int m = *modep;
    int d = threadIdx.x;
    float a = 0.f, bb = 0.f;
    if (d < DV) {
        float mu = cs[d] / (float)NN;
        float var = cs2[d] / (float)NN - mu * mu;
        var = fmaxf(var, 0.f);
        a = ldp(gamma, goff + d, m) * rsqrtf(var + 1e-5f);
        bb = ldp(beta, goff + d, m) - mu * a;
    }
    sc[d] = a; sh[d] = bb;
}

// ---------------------------------------------------------------- pooling (block/graph, 4 waves, LDS reduce; applies last BN affine)
__global__ void gstart_kernel(const int* __restrict__ batch, int* __restrict__ gs)
{
    int i = blockIdx.x * 256 + threadIdx.x;
    if (i >= NN) return;
    int b = batch[i];
    int pb = (i == 0) ? -1 : batch[i-1];
    for (int g = pb + 1; g <= b; ++g) gs[g] = i;
    if (i == NN - 1) for (int g = b + 1; g <= BG; ++g) gs[g] = NN;
}

__global__ __launch_bounds__(256)
void pool_kernel(const u16* __restrict__ H, const int* __restrict__ gs,
                 const float* __restrict__ sc, const float* __restrict__ sh,
                 u16* __restrict__ pooled)
{
    __shared__ float red[4][320];
    int b = blockIdx.x;
    int wv = threadIdx.x >> 6, lane = threadIdx.x & 63;
    int s = gs[b], e = gs[b+1];
    if (lane < 40) {
        int d0 = lane * 8;
        float a[8] = {0.f,0.f,0.f,0.f,0.f,0.f,0.f,0.f};
        for (int r = s + wv; r < e; r += 4) {
            uint4 row = *(const uint4*)(H + (size_t)r * DP + d0);
            const u16* p = (const u16*)&row;
            #pragma unroll
            for (int j = 0; j < 8; ++j) a[j] += b2f(p[j]);
        }
        #pragma unroll
        for (int j = 0; j < 8; ++j) red[wv][d0 + j] = a[j];
    }
    __syncthreads();
    if (wv == 0 && lane < 40) {
        int d0 = lane * 8;
        int c = e - s; if (c < 1) c = 1;
        float inv = 1.f / (float)c;
        union { uint4 v; u16 o[8]; } pk;
        #pragma unroll
        for (int j = 0; j < 8; ++j) {
            int d = d0 + j;
            float m = (red[0][d] + red[1][d] + red[2][d] + red[3][d]) * inv;
            pk.o[j] = f2b(m * sc[d] + sh[d]);
        }
        *(uint4*)(pooled + (size_t)b * DP + d0) = pk.v;
    }
}

// ---------------------------------------------------------------- final tiny GEMV (K=256 -> 2 fp32 outputs)
__global__ void pred_kernel(const u16* __restrict__ P2, const void* __restrict__ W3,
                            const void* __restrict__ b3, float* __restrict__ out,
                            const int* __restrict__ modep)
{
    const int m = *modep;
    int r = blockIdx.x, l = threadIdx.x;
    float a0 = 0.f, a1 = 0.f;
    for (int k = l; k < FH; k += 64) {
        float p = b2f(P2[(size_t)r*FH + k]);
        a0 += p * ldp(W3, k*2, m);
        a1 += p * ldp(W3, k*2 + 1, m);
    }
    for (int o = 32; o > 0; o >>= 1) {
        a0 += __shfl_down(a0, o);
        a1 += __shfl_down(a1, o);
    }
    if (l == 0) {
        out[(size_t)r*2]     = a0 + ldp(b3, 0, m);
        out[(size_t)r*2 + 1] = a1 + ldp(b3, 1, m);
    }
}

static inline int gemm_grid(int M, int Ncols) {
    int total = ((M + 127) / 128) * ((Ncols + 127) / 128);
    return ((total + 7) / 8) * 8;
}

// ---------------------------------------------------------------- launch
extern "C" void kernel_launch(void* const* d_in, const int* in_sizes, int n_in,
                              void* d_out, int out_size, void* d_ws, size_t ws_size,
                              hipStream_t stream)
{
    const int* x      = (const int*)d_in[0];
    const int* ei     = (const int*)d_in[1];
    const int* ea     = (const int*)d_in[2];
    const int* batch  = (const int*)d_in[3];
    const void* x_emb1 = d_in[4];
    const void* x_emb2 = d_in[5];
    const void* eemb1  = d_in[6];
    const void* eemb2  = d_in[7];
    const void* W1     = d_in[8];
    const void* b1     = d_in[9];
    const void* W2     = d_in[10];
    const void* b2     = d_in[11];
    const void* gamma  = d_in[12];
    const void* beta   = d_in[13];
    const void* Wf     = d_in[14];
    const void* bfe    = d_in[15];
    const void* Wp1    = d_in[16];
    const void* bp1    = d_in[17];
    const void* Wp2    = d_in[18];
    const void* bp2    = d_in[19];
    const void* Wp3    = d_in[20];
    const void* bp3    = d_in[21];
    float* outf = (float*)d_out;   // fp32 output: hf [4096*512] then pred [4096*2]

    char* ws = (char*)d_ws;
    size_t off = 0;
    auto carve = [&](size_t bytes) -> char* {
        size_t a = (off + 255) & ~(size_t)255; off = a + bytes; return ws + a;
    };

    u16* H      = (u16*)carve((size_t)NN * DP * 2);      // 64.0 MB (pre-BN after each layer)
    u16* AGGR   = (u16*)carve((size_t)NN * DP * 2);      // 64.0 MB
    u16* T      = (u16*)carve((size_t)CHUNK * D2P * 2);  // 64.1 MB (2 chunks)
    u16* POOLED = (u16*)carve((size_t)BG * DP * 2);
    u16* HFB    = (u16*)carve((size_t)BG * FEAT * 2);    // bf16 copy of hf for the MLP head
    u16* P1     = (u16*)carve((size_t)BG * FH * 2);
    u16* P2     = (u16*)carve((size_t)BG * FH * 2);
    u16* W1pT   = (u16*)carve((size_t)NL * D2P * DP * 2);
    u16* W2pT   = (u16*)carve((size_t)NL * DP * D2P * 2);
    u16* WfT    = (u16*)carve((size_t)FEAT * DP * 2);
    u16* Wp1T   = (u16*)carve((size_t)FH * FEAT * 2);
    u16* Wp2T   = (u16*)carve((size_t)FH * FH * 2);
    float* B1P  = (float*)carve((size_t)NL * D2P * 4);
    float* B2P  = (float*)carve((size_t)NL * DP * 4);
    float* BFP  = (float*)carve((size_t)FEAT * 4);
    float* BP1P = (float*)carve((size_t)FH * 4);
    float* BP2P = (float*)carve((size_t)FH * 4);
    int* INDEG  = (int*)carve((size_t)9 * NN * 4);   // indeg [N] then cnt [N*8]
    int* CNT    = INDEG + NN;
    int* ROWPTR = (int*)carve((size_t)(NN + 1) * 4);
    int* CURSOR = (int*)carve((size_t)NN * 4);
    int* COLIDX = (int*)carve((size_t)EE * 4);
    int* PART   = (int*)carve(512 * 4);
    float* CS   = (float*)carve(DP * 4);                 // fused BN stats (col sums)
    float* CS2  = (float*)carve(DP * 4);
    float* BNSC = (float*)carve((size_t)NL * DP * 4);    // per-layer BN scale
    float* BNSH = (float*)carve((size_t)NL * DP * 4);    // per-layer BN shift
    int* GS     = (int*)carve((size_t)(BG + 1) * 4);
    int* MODEP  = (int*)carve(4);
    (void)ws_size; (void)in_sizes; (void)n_in; (void)out_size;

    detect_kernel<<<1, 64, 0, stream>>>(W1, MODEP);

    const int PACK_TOTAL = NL*D2P*DP + NL*DP*D2P + FEAT*DP + FH*FEAT + FH*FH
                         + NL*D2P + NL*DP + FEAT + FH + FH;
    pack_kernel<<<(PACK_TOTAL + 255)/256, 256, 0, stream>>>(
        W1, W2, Wf, Wp1, Wp2, b1, b2, bfe, bp1, bp2,
        W1pT, W2pT, WfT, Wp1T, Wp2T, B1P, B2P, BFP, BP1P, BP2P, MODEP);
    fold_kernel<<<NL*8, 640, 0, stream>>>(W1, eemb1, eemb2, W1pT, MODEP);

    zero_int_kernel<<<2048, 256, 0, stream>>>(INDEG, (long)9 * NN);
    count_kernel<<<(EE + 255)/256, 256, 0, stream>>>(ei, ea, INDEG, CNT);

    const int NB = (NN + 255) / 256; // 391
    scan1_kernel<<<NB, 256, 0, stream>>>(INDEG, ROWPTR, PART, NN);
    scan2_kernel<<<1, 512, 0, stream>>>(PART, NB);
    scan3_kernel<<<(NN + 256)/256, 256, 0, stream>>>(ROWPTR, PART, CURSOR, NN);
    fill_kernel<<<(EE + 255)/256, 256, 0, stream>>>(ei, CURSOR, COLIDX);

    h0_kernel<<<NN, DP, 0, stream>>>(x, x_emb1, x_emb2, H, MODEP);
    gstart_kernel<<<(NN + 255)/256, 256, 0, stream>>>(batch, GS);

    for (int l = 0; l < NL; ++l) {
        if (l == 0)
            aggr_kernel<false><<<QN, DP, 0, stream>>>(H, ROWPTR, COLIDX, CNT,
                                                      nullptr, nullptr, AGGR);
        else
            aggr_kernel<true><<<QN, DP, 0, stream>>>(H, ROWPTR, COLIDX, CNT,
                                                     BNSC + (l-1)*DP, BNSH + (l-1)*DP, AGGR);
        zero_stats_kernel<<<1, DP, 0, stream>>>(CS, CS2);
        // GEMM1 -> relu -> T, GEMM2 -> H (pre-BN) + fused BN stats, chunked
        for (int r0 = 0; r0 < NN; r0 += CHUNK) {
            int mc = NN - r0; if (mc > CHUNK) mc = CHUNK;
            gemm_bt<1,false,false><<<gemm_grid(mc, D2P), 256, 0, stream>>>(
                AGGR + (size_t)r0*DP, DP, W1pT + (size_t)l*D2P*DP,
                B1P + l*D2P, T, nullptr, D2P, mc, D2P, DP, nullptr, nullptr);
            gemm_bt<0,false,true><<<gemm_grid(mc, DP), 256, 0, stream>>>(
                T, D2P, W2pT + (size_t)l*DP*D2P,
                B2P + l*DP, H + (size_t)r0*DP, nullptr, DP, mc, DP, D2P, CS, CS2);
        }
        bn_finalize<<<1, DP, 0, stream>>>(CS, CS2, gamma, beta, l*DV,
                                          BNSC + l*DP, BNSH + l*DP, MODEP);
    }

    pool_kernel<<<BG, 256, 0, stream>>>(H, GS, BNSC + 4*DP, BNSH + 4*DP, POOLED);
    // hf: fp32 -> d_out[0 : 4096*512], bf16 copy -> HFB for the MLP head
    gemm_bt<0,true,false><<<gemm_grid(BG, FEAT), 256, 0, stream>>>(
        POOLED, DP, WfT, BFP, HFB, outf, FEAT, BG, FEAT, DP, nullptr, nullptr);
    gemm_bt<2,false,false><<<gemm_grid(BG, FH), 256, 0, stream>>>(
        HFB, FEAT, Wp1T, BP1P, P1, nullptr, FH, BG, FH, FEAT, nullptr, nullptr);
    gemm_bt<2,false,false><<<gemm_grid(BG, FH), 256, 0, stream>>>(
        P1, FH, Wp2T, BP2P, P2, nullptr, FH, BG, FH, FH, nullptr, nullptr);
    pred_kernel<<<BG, 64, 0, stream>>>(P2, Wp3, bp3, outf + (size_t)BG*FEAT, MODEP);
}

// Round 12
// 1618.502 us; speedup vs baseline: 1.7589x; 1.1493x over previous
//
#include <hip/hip_runtime.h>
#include <cstdint>
#include <cstddef>

typedef unsigned short u16;
typedef __bf16 bf16x8 __attribute__((ext_vector_type(8)));
typedef float  f32x4  __attribute__((ext_vector_type(4)));

#define NN 100000
#define EE 200000
#define BG 4096
#define DV 300
#define DP 320
#define D2 600
#define D2P 640
#define FEAT 512
#define FH 256
#define NL 5
#define CHUNK 50048   // 391 * 128; 2 chunks cover 100000 rows
#define QN (NN/8)     // 12500 aggr blocks, 8 nodes each (8 indep gather chains)

__device__ __forceinline__ float b2f(u16 u) {
    union { float f; unsigned int i; } x; x.i = ((unsigned int)u) << 16; return x.f;
}
__device__ __forceinline__ u16 f2b(float f) {
    union { float f; unsigned int i; } x; x.f = f;
    unsigned int r = (x.i + 0x7FFFu + ((x.i >> 16) & 1u)) >> 16;
    return (u16)r;
}
// mode-aware parameter load: m==1 -> fp32 data, m==0 -> bf16 data
__device__ __forceinline__ float ldp(const void* p, size_t i, int m) {
    return m ? ((const float*)p)[i] : b2f(((const u16*)p)[i]);
}

// ---------------------------------------------------------------- dtype detection
__global__ void detect_kernel(const void* w1raw, int* mode) {
    if (threadIdx.x != 0 || blockIdx.x != 0) return;
    const u16* p = (const u16*)w1raw;
    int cnt = 0;
    for (int i = 0; i < 128; ++i) {
        u16 v = p[2 * i];
        int e = (v >> 7) & 0xFF;
        if (e >= 100 && e <= 135) ++cnt;
    }
    *mode = (cnt >= 100) ? 0 : 1;   // 0 = bf16, 1 = fp32
}

// ---------------------------------------------------------------- utility
__global__ void zero_int_kernel(int* __restrict__ p, long n) {
    long i = (long)blockIdx.x * blockDim.x + threadIdx.x;
    long stride = (long)gridDim.x * blockDim.x;
    for (; i < n; i += stride) p[i] = 0;
}

__global__ void zero_stats_kernel(float* __restrict__ a, float* __restrict__ b) {
    int t = threadIdx.x; a[t] = 0.f; b[t] = 0.f;
}

// ---------------------------------------------------------------- weight packing
__global__ void pack_kernel(const void* __restrict__ W1, const void* __restrict__ W2,
                            const void* __restrict__ Wf, const void* __restrict__ Wp1,
                            const void* __restrict__ Wp2,
                            const void* __restrict__ b1, const void* __restrict__ b2,
                            const void* __restrict__ bfe, const void* __restrict__ bp1,
                            const void* __restrict__ bp2,
                            u16* __restrict__ W1pT, u16* __restrict__ W2pT,
                            u16* __restrict__ WfT, u16* __restrict__ Wp1T, u16* __restrict__ Wp2T,
                            float* __restrict__ b1p, float* __restrict__ b2p,
                            float* __restrict__ bfp, float* __restrict__ bp1p, float* __restrict__ bp2p,
                            const int* __restrict__ modep)
{
    const int m = *modep;
    const int s1 = NL*D2P*DP, s2 = NL*DP*D2P, s3 = FEAT*DP, s4 = FH*FEAT, s5 = FH*FH;
    const int s6 = NL*D2P, s7 = NL*DP, s8 = FEAT, s9 = FH, s10 = FH;
    int idx = blockIdx.x * 256 + threadIdx.x;
    if (idx < s1) { // W1pT[l][n][k]
        int l = idx / (D2P*DP), r = idx % (D2P*DP), n = r / DP, k = r % DP;
        u16 v = 0;
        if (n < D2) {
            if (k < DV) v = f2b(ldp(W1, ((size_t)l*DV + k)*D2 + n, m));
            else if (k < DV + 8) return;   // fold_kernel owns these
        }
        W1pT[idx] = v; return;
    } idx -= s1;
    if (idx < s2) { // W2pT[l][n<320][k<640] = W2[l][k][n]
        int l = idx / (DP*D2P), r = idx % (DP*D2P), n = r / D2P, k = r % D2P;
        W2pT[idx] = (n < DV && k < D2) ? f2b(ldp(W2, ((size_t)l*D2 + k)*DV + n, m)) : (u16)0; return;
    } idx -= s2;
    if (idx < s3) { int n = idx / DP, k = idx % DP;
        WfT[idx] = (k < DV) ? f2b(ldp(Wf, (size_t)k*FEAT + n, m)) : (u16)0; return; } idx -= s3;
    if (idx < s4) { int n = idx / FEAT, k = idx % FEAT;
        Wp1T[idx] = f2b(ldp(Wp1, (size_t)k*FH + n, m)); return; } idx -= s4;
    if (idx < s5) { int n = idx / FH, k = idx % FH;
        Wp2T[idx] = f2b(ldp(Wp2, (size_t)k*FH + n, m)); return; } idx -= s5;
    if (idx < s6) { int l = idx / D2P, n = idx % D2P;
        b1p[idx] = (n < D2) ? ldp(b1, l*D2 + n, m) : 0.f; return; } idx -= s6;
    if (idx < s7) { int l = idx / DP, n = idx % DP;
        b2p[idx] = (n < DV) ? ldp(b2, l*DV + n, m) : 0.f; return; } idx -= s7;
    if (idx < s8) { bfp[idx] = ldp(bfe, idx, m); return; } idx -= s8;
    if (idx < s9) { bp1p[idx] = ldp(bp1, idx, m); return; } idx -= s9;
    if (idx < s10) { bp2p[idx] = ldp(bp2, idx, m); return; }
}

// EMB @ W1 fold: W1pT[l][n][300+bin] = sum_d emb[l][bin][d] * W1[l][d][n].
__global__ void fold_kernel(const void* __restrict__ W1,
                            const void* __restrict__ eemb1, const void* __restrict__ eemb2,
                            u16* __restrict__ W1pT, const int* __restrict__ modep)
{
    const int m = *modep;
    __shared__ float e[DV];
    int b = blockIdx.x;            // 0..NL*8-1
    int l = b >> 3, bin = b & 7;
    int n = threadIdx.x;
    for (int d = n; d < DV; d += 640)
        e[d] = (bin < 5) ? ldp(eemb1, ((size_t)l*5 + bin)*DV + d, m)
                         : ldp(eemb2, ((size_t)l*3 + (bin-5))*DV + d, m);
    __syncthreads();
    if (n >= D2) return;
    float acc = 0.f;
    for (int d = 0; d < DV; ++d)
        acc += e[d] * ldp(W1, ((size_t)l*DV + d)*D2 + n, m);
    W1pT[((size_t)l*D2P + n)*DP + DV + bin] = f2b(acc);
}

// ---------------------------------------------------------------- CSR build
__global__ void count_kernel(const int* __restrict__ ei, const int* __restrict__ ea,
                             int* __restrict__ indeg, int* __restrict__ cnt)
{
    int e = blockIdx.x * 256 + threadIdx.x;
    if (e >= EE) return;
    int dst = ei[EE + e];
    atomicAdd(&indeg[dst], 1);
    atomicAdd(&cnt[dst*8 + ea[e*2]], 1);
    atomicAdd(&cnt[dst*8 + 5 + ea[e*2+1]], 1);
}

__global__ void scan1_kernel(const int* __restrict__ in, int* __restrict__ out,
                             int* __restrict__ partials, int n)
{
    __shared__ int sm[256];
    int t = threadIdx.x, gi = blockIdx.x * 256 + t;
    int v = (gi < n) ? in[gi] : 0;
    sm[t] = v; __syncthreads();
    int acc = v;
    for (int off = 1; off < 256; off <<= 1) {
        int other = (t >= off) ? sm[t - off] : 0;
        __syncthreads();
        acc += other; sm[t] = acc;
        __syncthreads();
    }
    if (gi < n) out[gi] = acc - v;
    if (t == 255) partials[blockIdx.x] = acc;
}

__global__ void scan2_kernel(int* __restrict__ partials, int nb)
{
    __shared__ int sm[512];
    int t = threadIdx.x;
    int v = (t < nb) ? partials[t] : 0;
    sm[t] = v; __syncthreads();
    int acc = v;
    for (int off = 1; off < 512; off <<= 1) {
        int other = (t >= off) ? sm[t - off] : 0;
        __syncthreads();
        acc += other; sm[t] = acc;
        __syncthreads();
    }
    if (t < nb) partials[t] = acc - v;
}

__global__ void scan3_kernel(int* __restrict__ rowptr, const int* __restrict__ partials,
                             int* __restrict__ cursor, int n)
{
    int i = blockIdx.x * 256 + threadIdx.x;
    if (i < n) {
        int v = rowptr[i] + partials[i >> 8];
        rowptr[i] = v; cursor[i] = v;
    }
    if (i == n) rowptr[n] = EE;
}

__global__ void fill_kernel(const int* __restrict__ ei, int* __restrict__ cursor,
                            int* __restrict__ colidx)
{
    int e = blockIdx.x * 256 + threadIdx.x;
    if (e >= EE) return;
    int src = ei[e], dst = ei[EE + e];
    int pos = atomicAdd(&cursor[dst], 1);
    colidx[pos] = src;
}

// ---------------------------------------------------------------- node init
__global__ void h0_kernel(const int* __restrict__ x, const void* __restrict__ e1,
                          const void* __restrict__ e2, u16* __restrict__ H,
                          const int* __restrict__ modep)
{
    const int m = *modep;
    int i = blockIdx.x, d = threadIdx.x;
    u16 r = 0;
    if (d < DV) {
        int a = x[i*2], b = x[i*2+1];
        r = f2b(ldp(e1, (size_t)a*DV + d, m) + ldp(e2, (size_t)b*DV + d, m));
    }
    H[(size_t)i*DP + d] = r;
}

// ---------------------------------------------------------------- aggregation (8 nodes/block for 8x memory-level parallelism)
template<bool BN>
__global__ __launch_bounds__(320)
void aggr_kernel(const u16* __restrict__ H, const int* __restrict__ rowptr,
                 const int* __restrict__ colidx, const int* __restrict__ cnt,
                 const float* __restrict__ sc, const float* __restrict__ sh,
                 u16* __restrict__ out)
{
    const int b = blockIdx.x, d = threadIdx.x;
    int node[8];
    #pragma unroll
    for (int k = 0; k < 8; ++k) node[k] = b + k * QN;

    if (d < DV) {
        float scv = BN ? sc[d] : 1.f, shv = BN ? sh[d] : 0.f;
        float acc[8];
        int e0[8], deg[8]; int maxdeg = 0;
        #pragma unroll
        for (int k = 0; k < 8; ++k) {
            e0[k] = rowptr[node[k]];
            deg[k] = rowptr[node[k] + 1] - e0[k];
            maxdeg = max(maxdeg, deg[k]);
            float h = b2f(H[(size_t)node[k]*DP + d]);
            if (BN) h = fmaxf(h * scv + shv, 0.f);
            acc[k] = h;
        }
        for (int j = 0; j < maxdeg; ++j) {
            int idx[8];
            #pragma unroll
            for (int k = 0; k < 8; ++k) {
                int jj = e0[k] + j; if (jj > EE - 1) jj = EE - 1;
                idx[k] = (j < deg[k]) ? colidx[jj] : node[k];
            }
            float hv[8];
            #pragma unroll
            for (int k = 0; k < 8; ++k) hv[k] = b2f(H[(size_t)idx[k]*DP + d]);
            #pragma unroll
            for (int k = 0; k < 8; ++k) {
                float h = hv[k];
                if (BN) h = fmaxf(h * scv + shv, 0.f);
                if (j < deg[k]) acc[k] += h;
            }
        }
        #pragma unroll
        for (int k = 0; k < 8; ++k) out[(size_t)node[k]*DP + d] = f2b(acc[k]);
    } else {
        #pragma unroll
        for (int k = 0; k < 8; ++k) {
            float v = 0.f;
            if (d < DV + 8) {
                int c = cnt[node[k]*8 + (d - DV)];
                if (d == DV + 4 || d == DV + 5) c += 1;   // self-loop attr (4,0)
                v = (float)c;
            }
            out[(size_t)node[k]*DP + d] = f2b(v);
        }
    }
}

// ---------------------------------------------------------------- bf16 MFMA GEMM (4 waves, VGPR~72, 5 blocks/CU — occupancy governs
// at short K). 128x128 tile, BK=64, XOR-swizzled LDS, XCD-aware tile swizzle.
// Epilogue (bf16 path): 2-pass LDS transform reusing As -> coalesced uint4
// stores (16B/lane) instead of 64x 2B scalar stores. q-rotated columns keep
// the transform conflict-free. EPI: 0 none, 1 relu, 2 softplus.
// STATS: fused per-column BN sums. F32OUT: scalar dual-store path (head hf).
template<int EPI, bool F32OUT, bool STATS>
__global__ __launch_bounds__(256)
void gemm_bt(const u16* __restrict__ A, int lda,
             const u16* __restrict__ Bt,
             const float* __restrict__ bias,
             u16* __restrict__ C, float* __restrict__ Cf, int ldc,
             int M, int Ncols, int K,
             float* __restrict__ cs, float* __restrict__ cs2)
{
    const int MT = (M + 127) >> 7, NT = (Ncols + 127) >> 7;
    const int total = MT * NT;
    int id = blockIdx.x;
    int nper = (total + 7) >> 3;
    int slot = (id & 7) * nper + (id >> 3);   // transpose over XCDs: n-tiles run on one XCD
    if (slot >= total) return;
    const int m0 = (slot / NT) * 128;
    const int n0 = (slot % NT) * 128;

    __shared__ __align__(16) u16 As[128*64];
    __shared__ __align__(16) u16 Bs[128*64];
    const int t = threadIdx.x;
    const int w = t >> 6, l = t & 63;
    const int wm = (w & 1) * 64, wn = (w >> 1) * 64;
    const int srow = l >> 3;                         // row within 8-row chunk
    const int sg   = ((l & 7) ^ srow) * 8;           // swizzled k-granule offset (elems)
    const int fr = l & 15, q = l >> 4;

    f32x4 acc[4][4] = {};

    for (int k0 = 0; k0 < K; k0 += 64) {
        #pragma unroll
        for (int i = 0; i < 8; ++i) {
            int cc = w * 8 + i;                      // 0..31, wave-uniform
            int rl = (cc & 15) * 8 + srow;           // local row 0..127
            if (cc < 16) {                           // A tile
                int row = m0 + rl; if (row >= M) row = M - 1;
                const u16* gp = A + (size_t)row * lda + (k0 + sg);
                __builtin_amdgcn_global_load_lds((__attribute__((address_space(1))) void*)gp,
                                                 (__attribute__((address_space(3))) void*)(As + cc*512), 16, 0, 0);
            } else {                                 // B tile
                int row = n0 + rl; if (row >= Ncols) row = Ncols - 1;
                const u16* gp = Bt + (size_t)row * K + (k0 + sg);
                __builtin_amdgcn_global_load_lds((__attribute__((address_space(1))) void*)gp,
                                                 (__attribute__((address_space(3))) void*)(Bs + (cc-16)*512), 16, 0, 0);
            }
        }
        asm volatile("s_waitcnt vmcnt(0)" ::: "memory");
        __syncthreads();

        #pragma unroll
        for (int s = 0; s < 2; ++s) {
            bf16x8 af[4], bv[4];
            #pragma unroll
            for (int mi = 0; mi < 4; ++mi) {
                int R = wm + mi*16 + fr;
                int g = (s*4 + q) ^ (R & 7);
                af[mi] = *reinterpret_cast<const bf16x8*>(As + R*64 + g*8);
            }
            #pragma unroll
            for (int ni = 0; ni < 4; ++ni) {
                int R = wn + ni*16 + fr;
                int g = (s*4 + q) ^ (R & 7);
                bv[ni] = *reinterpret_cast<const bf16x8*>(Bs + R*64 + g*8);
            }
            #pragma unroll
            for (int mi = 0; mi < 4; ++mi)
                #pragma unroll
                for (int ni = 0; ni < 4; ++ni)
                    acc[mi][ni] = __builtin_amdgcn_mfma_f32_16x16x32_bf16(af[mi], bv[ni], acc[mi][ni], 0, 0, 0);
        }
        __syncthreads();
    }

    const int orow = q * 4, ocol = l & 15;
    // bias + activation (values kept in acc) + fused stats
    #pragma unroll
    for (int ni = 0; ni < 4; ++ni) {
        int col = n0 + wn + ni*16 + ocol;
        float bvv = (col < Ncols) ? bias[col] : 0.f;
        float s = 0.f, s2 = 0.f;
        #pragma unroll
        for (int mi = 0; mi < 4; ++mi) {
            #pragma unroll
            for (int r = 0; r < 4; ++r) {
                float v = acc[mi][ni][r] + bvv;
                if (EPI == 1) v = fmaxf(v, 0.f);
                else if (EPI == 2) v = fmaxf(v, 0.f) + log1pf(expf(-fabsf(v)));
                acc[mi][ni][r] = v;
                if (STATS) {
                    int row = m0 + wm + mi*16 + orow + r;
                    if (row < M && col < Ncols) { s += v; s2 += v * v; }
                }
            }
        }
        if (STATS) {
            s  += __shfl_xor(s, 16);  s  += __shfl_xor(s, 32);
            s2 += __shfl_xor(s2, 16); s2 += __shfl_xor(s2, 32);
            if (q == 0 && col < Ncols) {
                atomicAdd(&cs[col], s);
                atomicAdd(&cs2[col], s2);
            }
        }
    }

    if (!F32OUT) {
        // 2-pass LDS transform: half-tile (64 rows) staged in As, then uint4 stores
        #pragma unroll
        for (int p = 0; p < 2; ++p) {
            if ((w & 1) == p) {
                #pragma unroll
                for (int mi = 0; mi < 4; ++mi)
                    #pragma unroll
                    for (int ni = 0; ni < 4; ++ni)
                        #pragma unroll
                        for (int r = 0; r < 4; ++r) {
                            int lr = mi*16 + q*4 + r;                 // 0..63
                            int lc = wn + ni*16 + ocol;               // 0..127
                            int slc = (lc + q*16) & 127;              // q-rotation: conflict-free
                            As[lr*128 + slc] = f2b(acc[mi][ni][r]);
                        }
            }
            __syncthreads();
            #pragma unroll
            for (int j = 0; j < 4; ++j) {
                int u = t*4 + j;                                       // 0..1023
                int lr = u >> 4, lc8 = (u & 15) * 8;
                int slc = (lc8 + ((lr >> 2) & 3) * 16) & 127;
                int grow = m0 + p*64 + lr, gcol = n0 + lc8;
                if (grow < M && gcol < Ncols)
                    *(uint4*)(C + (size_t)grow*ldc + gcol) = *(const uint4*)(As + lr*128 + slc);
            }
            __syncthreads();
        }
    } else {
        #pragma unroll
        for (int ni = 0; ni < 4; ++ni) {
            int col = n0 + wn + ni*16 + ocol;
            if (col >= Ncols) continue;
            #pragma unroll
            for (int mi = 0; mi < 4; ++mi) {
                #pragma unroll
                for (int r = 0; r < 4; ++r) {
                    int row = m0 + wm + mi*16 + orow + r;
                    if (row < M) {
                        float v = acc[mi][ni][r];
                        C[(size_t)row * ldc + col] = f2b(v);
                        Cf[(size_t)row * ldc + col] = v;
                    }
                }
            }
        }
    }
}

// ---------------------------------------------------------------- BN finalize (stats from GEMM2 epilogue; self-zeroes for next layer)
__global__ void bn_finalize(float* __restrict__ cs, float* __restrict__ cs2,
                            const void* __restrict__ gamma, const void* __restrict__ beta,
                            int goff, float* __restrict__ sc, float* __restrict__ sh,
                            const int* __restrict__ modep)
{
    const int m = *modep;
    int d = threadIdx.x;
    float s = cs[d], s2 = cs2[d];
    cs[d] = 0.f; cs2[d] = 0.f;
    float a = 0.f, bb = 0.f;
    if (d < DV) {
        float mu = s / (float)NN;
        float var = s2 / (float)NN - mu * mu;
        var = fmaxf(var, 0.f);
        a = ldp(gamma, goff + d, m) * rsqrtf(var + 1e-5f);
        bb = ldp(beta, goff + d, m) - mu * a;
    }
    sc[d] = a; sh[d] = bb;
}

// ---------------------------------------------------------------- pooling
__global__ void gstart_kernel(const int* __restrict__ batch, int* __restrict__ gs)
{
    int i = blockIdx.x * 256 + threadIdx.x;
    if (i >= NN) return;
    int b = batch[i];
    int pb = (i == 0) ? -1 : batch[i-1];
    for (int g = pb + 1; g <= b; ++g) gs[g] = i;
    if (i == NN - 1) for (int g = b + 1; g <= BG; ++g) gs[g] = NN;
}

__global__ __launch_bounds__(256)
void pool_kernel(const u16* __restrict__ H, const int* __restrict__ gs,
                 const float* __restrict__ sc, const float* __restrict__ sh,
                 u16* __restrict__ pooled)
{
    __shared__ float red[4][320];
    int b = blockIdx.x;
    int wv = threadIdx.x >> 6, lane = threadIdx.x & 63;
    int s = gs[b], e = gs[b+1];
    if (lane < 40) {
        int d0 = lane * 8;
        float a[8] = {0.f,0.f,0.f,0.f,0.f,0.f,0.f,0.f};
        for (int r = s + wv; r < e; r += 4) {
            uint4 row = *(const uint4*)(H + (size_t)r * DP + d0);
            const u16* p = (const u16*)&row;
            #pragma unroll
            for (int j = 0; j < 8; ++j) a[j] += b2f(p[j]);
        }
        #pragma unroll
        for (int j = 0; j < 8; ++j) red[wv][d0 + j] = a[j];
    }
    __syncthreads();
    if (wv == 0 && lane < 40) {
        int d0 = lane * 8;
        int c = e - s; if (c < 1) c = 1;
        float inv = 1.f / (float)c;
        union { uint4 v; u16 o[8]; } pk;
        #pragma unroll
        for (int j = 0; j < 8; ++j) {
            int d = d0 + j;
            float m = (red[0][d] + red[1][d] + red[2][d] + red[3][d]) * inv;
            pk.o[j] = f2b(m * sc[d] + sh[d]);
        }
        *(uint4*)(pooled + (size_t)b * DP + d0) = pk.v;
    }
}

// ---------------------------------------------------------------- final tiny GEMV (K=256 -> 2 fp32 outputs)
__global__ void pred_kernel(const u16* __restrict__ P2, const void* __restrict__ W3,
                            const void* __restrict__ b3, float* __restrict__ out,
                            const int* __restrict__ modep)
{
    const int m = *modep;
    int r = blockIdx.x, l = threadIdx.x;
    float a0 = 0.f, a1 = 0.f;
    for (int k = l; k < FH; k += 64) {
        float p = b2f(P2[(size_t)r*FH + k]);
        a0 += p * ldp(W3, k*2, m);
        a1 += p * ldp(W3, k*2 + 1, m);
    }
    for (int o = 32; o > 0; o >>= 1) {
        a0 += __shfl_down(a0, o);
        a1 += __shfl_down(a1, o);
    }
    if (l == 0) {
        out[(size_t)r*2]     = a0 + ldp(b3, 0, m);
        out[(size_t)r*2 + 1] = a1 + ldp(b3, 1, m);
    }
}

static inline int gemm_grid(int M, int Ncols) {
    int total = ((M + 127) / 128) * ((Ncols + 127) / 128);
    return ((total + 7) / 8) * 8;
}

// ---------------------------------------------------------------- launch
extern "C" void kernel_launch(void* const* d_in, const int* in_sizes, int n_in,
                              void* d_out, int out_size, void* d_ws, size_t ws_size,
                              hipStream_t stream)
{
    const int* x      = (const int*)d_in[0];
    const int* ei     = (const int*)d_in[1];
    const int* ea     = (const int*)d_in[2];
    const int* batch  = (const int*)d_in[3];
    const void* x_emb1 = d_in[4];
    const void* x_emb2 = d_in[5];
    const void* eemb1  = d_in[6];
    const void* eemb2  = d_in[7];
    const void* W1     = d_in[8];
    const void* b1     = d_in[9];
    const void* W2     = d_in[10];
    const void* b2     = d_in[11];
    const void* gamma  = d_in[12];
    const void* beta   = d_in[13];
    const void* Wf     = d_in[14];
    const void* bfe    = d_in[15];
    const void* Wp1    = d_in[16];
    const void* bp1    = d_in[17];
    const void* Wp2    = d_in[18];
    const void* bp2    = d_in[19];
    const void* Wp3    = d_in[20];
    const void* bp3    = d_in[21];
    float* outf = (float*)d_out;   // fp32 output: hf [4096*512] then pred [4096*2]

    char* ws = (char*)d_ws;
    size_t off = 0;
    auto carve = [&](size_t bytes) -> char* {
        size_t a = (off + 255) & ~(size_t)255; off = a + bytes; return ws + a;
    };

    u16* H      = (u16*)carve((size_t)NN * DP * 2);      // 64.0 MB (pre-BN after each layer)
    u16* AGGR   = (u16*)carve((size_t)NN * DP * 2);      // 64.0 MB
    u16* T      = (u16*)carve((size_t)CHUNK * D2P * 2);  // 64.1 MB (2 chunks)
    u16* POOLED = (u16*)carve((size_t)BG * DP * 2);
    u16* HFB    = (u16*)carve((size_t)BG * FEAT * 2);    // bf16 copy of hf for the MLP head
    u16* P1     = (u16*)carve((size_t)BG * FH * 2);
    u16* P2     = (u16*)carve((size_t)BG * FH * 2);
    u16* W1pT   = (u16*)carve((size_t)NL * D2P * DP * 2);
    u16* W2pT   = (u16*)carve((size_t)NL * DP * D2P * 2);
    u16* WfT    = (u16*)carve((size_t)FEAT * DP * 2);
    u16* Wp1T   = (u16*)carve((size_t)FH * FEAT * 2);
    u16* Wp2T   = (u16*)carve((size_t)FH * FH * 2);
    float* B1P  = (float*)carve((size_t)NL * D2P * 4);
    float* B2P  = (float*)carve((size_t)NL * DP * 4);
    float* BFP  = (float*)carve((size_t)FEAT * 4);
    float* BP1P = (float*)carve((size_t)FH * 4);
    float* BP2P = (float*)carve((size_t)FH * 4);
    int* INDEG  = (int*)carve((size_t)9 * NN * 4);   // indeg [N] then cnt [N*8]
    int* CNT    = INDEG + NN;
    int* ROWPTR = (int*)carve((size_t)(NN + 1) * 4);
    int* CURSOR = (int*)carve((size_t)NN * 4);
    int* COLIDX = (int*)carve((size_t)EE * 4);
    int* PART   = (int*)carve(512 * 4);
    float* CS   = (float*)carve(DP * 4);                 // fused BN stats (col sums)
    float* CS2  = (float*)carve(DP * 4);
    float* BNSC = (float*)carve((size_t)NL * DP * 4);    // per-layer BN scale
    float* BNSH = (float*)carve((size_t)NL * DP * 4);    // per-layer BN shift
    int* GS     = (int*)carve((size_t)(BG + 1) * 4);
    int* MODEP  = (int*)carve(4);
    (void)ws_size; (void)in_sizes; (void)n_in; (void)out_size;

    detect_kernel<<<1, 64, 0, stream>>>(W1, MODEP);

    const int PACK_TOTAL = NL*D2P*DP + NL*DP*D2P + FEAT*DP + FH*FEAT + FH*FH
                         + NL*D2P + NL*DP + FEAT + FH + FH;
    pack_kernel<<<(PACK_TOTAL + 255)/256, 256, 0, stream>>>(
        W1, W2, Wf, Wp1, Wp2, b1, b2, bfe, bp1, bp2,
        W1pT, W2pT, WfT, Wp1T, Wp2T, B1P, B2P, BFP, BP1P, BP2P, MODEP);
    fold_kernel<<<NL*8, 640, 0, stream>>>(W1, eemb1, eemb2, W1pT, MODEP);

    zero_int_kernel<<<2048, 256, 0, stream>>>(INDEG, (long)9 * NN);
    zero_stats_kernel<<<1, DP, 0, stream>>>(CS, CS2);
    count_kernel<<<(EE + 255)/256, 256, 0, stream>>>(ei, ea, INDEG, CNT);

    const int NB = (NN + 255) / 256; // 391
    scan1_kernel<<<NB, 256, 0, stream>>>(INDEG, ROWPTR, PART, NN);
    scan2_kernel<<<1, 512, 0, stream>>>(PART, NB);
    scan3_kernel<<<(NN + 256)/256, 256, 0, stream>>>(ROWPTR, PART, CURSOR, NN);
    fill_kernel<<<(EE + 255)/256, 256, 0, stream>>>(ei, CURSOR, COLIDX);

    h0_kernel<<<NN, DP, 0, stream>>>(x, x_emb1, x_emb2, H, MODEP);
    gstart_kernel<<<(NN + 255)/256, 256, 0, stream>>>(batch, GS);

    for (int l = 0; l < NL; ++l) {
        if (l == 0)
            aggr_kernel<false><<<QN, DP, 0, stream>>>(H, ROWPTR, COLIDX, CNT,
                                                      nullptr, nullptr, AGGR);
        else
            aggr_kernel<true><<<QN, DP, 0, stream>>>(H, ROWPTR, COLIDX, CNT,
                                                     BNSC + (l-1)*DP, BNSH + (l-1)*DP, AGGR);
        // GEMM1 -> relu -> T, GEMM2 -> H (pre-BN) + fused BN stats, chunked
        for (int r0 = 0; r0 < NN; r0 += CHUNK) {
            int mc = NN - r0; if (mc > CHUNK) mc = CHUNK;
            gemm_bt<1,false,false><<<gemm_grid(mc, D2P), 256, 0, stream>>>(
                AGGR + (size_t)r0*DP, DP, W1pT + (size_t)l*D2P*DP,
                B1P + l*D2P, T, nullptr, D2P, mc, D2P, DP, nullptr, nullptr);
            gemm_bt<0,false,true><<<gemm_grid(mc, DP), 256, 0, stream>>>(
                T, D2P, W2pT + (size_t)l*DP*D2P,
                B2P + l*DP, H + (size_t)r0*DP, nullptr, DP, mc, DP, D2P, CS, CS2);
        }
        bn_finalize<<<1, DP, 0, stream>>>(CS, CS2, gamma, beta, l*DV,
                                          BNSC + l*DP, BNSH + l*DP, MODEP);
    }

    pool_kernel<<<BG, 256, 0, stream>>>(H, GS, BNSC + 4*DP, BNSH + 4*DP, POOLED);
    // hf: fp32 -> d_out[0 : 4096*512], bf16 copy -> HFB for the MLP head
    gemm_bt<0,true,false><<<gemm_grid(BG, FEAT), 256, 0, stream>>>(
        POOLED, DP, WfT, BFP, HFB, outf, FEAT, BG, FEAT, DP, nullptr, nullptr);
    gemm_bt<2,false,false><<<gemm_grid(BG, FH), 256, 0, stream>>>(
        HFB, FEAT, Wp1T, BP1P, P1, nullptr, FH, BG, FH, FEAT, nullptr, nullptr);
    gemm_bt<2,false,false><<<gemm_grid(BG, FH), 256, 0, stream>>>(
        P1, FH, Wp2T, BP2P, P2, nullptr, FH, BG, FH, FH, nullptr, nullptr);
    pred_kernel<<<BG, 64, 0, stream>>>(P2, Wp3, bp3, outf + (size_t)BG*FEAT, MODEP);
}